// Round 1
// 678.510 us; speedup vs baseline: 1.1255x; 1.1255x over previous
//
#include <hip/hip_runtime.h>
#include <hip/hip_bf16.h>
#include <math.h>

// B=16,S=1024 -> M=16384 tokens; D=1024, F=4096, E=8, R=32, SCALING=0.5
// Big GEMMs: 256x256 tile, BK=64, 8 waves, 8-phase counted-vmcnt schedule
// (T1+T2+T3+T4+T5). LoRA-B folded into K as packed extension columns so
// GEMM1 is [M,1280]x[4096,1280]^T and GEMM2 is [M,4352]x[1024,4352]^T.
// LoRA-A (N=256) stays on the m97-style 128x128 kernel.

#define M_TOK 16384
#define DIM_D 1024
#define DIM_F 4096
#define NEXP 8
#define RANK 32
#define NER 256   // NEXP*RANK
#define K1 1280   // DIM_D + NER
#define K2 4352   // DIM_F + NER

typedef __attribute__((ext_vector_type(8))) short bf16x8;
typedef __attribute__((ext_vector_type(4))) short sh4;
typedef __attribute__((ext_vector_type(4))) float f32x4;

__device__ inline short f2bs(float x) {
  __hip_bfloat16 h = __float2bfloat16(x);
  return *reinterpret_cast<short*>(&h);
}

__device__ inline void async16(const void* g, void* l) {
  __builtin_amdgcn_global_load_lds(
      (__attribute__((address_space(1))) void*)(g),
      (__attribute__((address_space(3))) void*)(l), 16, 0, 0);
}

// ---------- fp32 -> bf16 with output pitch (8 elems/thread) ----------
__global__ __launch_bounds__(256) void convert_pitched(
    const float* __restrict__ in, short* __restrict__ out,
    int c8, int opitch, int n8)
{
  const int i = blockIdx.x * 256 + threadIdx.x;
  if (i >= n8) return;
  const int row = i / c8;
  const int c = (i % c8) * 8;
  const float4* p = (const float4*)(in + (size_t)row * (c8 * 8) + c);
  float4 u = p[0], v = p[1];
  bf16x8 r;
  r[0] = f2bs(u.x); r[1] = f2bs(u.y); r[2] = f2bs(u.z); r[3] = f2bs(u.w);
  r[4] = f2bs(v.x); r[5] = f2bs(v.y); r[6] = f2bs(v.z); r[7] = f2bs(v.w);
  *(bf16x8*)(out + (size_t)row * opitch + c) = r;
}

// ---------- pack LoRA-B [E,N,R] fp32 -> [N, opitch] bf16 at col ooff ----------
__global__ __launch_bounds__(256) void pack_lorab(
    const float* __restrict__ in, short* __restrict__ out,
    int Nn, int opitch, int ooff, int n8)
{
  const int i = blockIdx.x * 256 + threadIdx.x;
  if (i >= n8) return;
  const int e = i / (Nn * 4);
  const int rem = i % (Nn * 4);
  const int n = rem >> 2;
  const int r8 = (rem & 3) * 8;
  const float4* p = (const float4*)(in + ((size_t)e * Nn + n) * RANK + r8);
  float4 u = p[0], v = p[1];
  bf16x8 r;
  r[0] = f2bs(u.x); r[1] = f2bs(u.y); r[2] = f2bs(u.z); r[3] = f2bs(u.w);
  r[4] = f2bs(v.x); r[5] = f2bs(v.y); r[6] = f2bs(v.z); r[7] = f2bs(v.w);
  *(bf16x8*)(out + (size_t)n * opitch + ooff + e * RANK + r8) = r;
}

// ---------- router (one wave per token) + fused x->bf16 into xb_wide ----------
__global__ __launch_bounds__(256) void router_kernel(
    const float* __restrict__ X,     // [M, D]
    const float* __restrict__ RW,    // [E, D]
    const float* __restrict__ RB,    // [E]
    float* __restrict__ routing_out, // [M, E]
    float* __restrict__ ec_out,      // [M, E]
    int* __restrict__ idx_out,       // [M]
    short* __restrict__ XB)          // [M, K1] bf16, cols 0..1023
{
  const int wave = threadIdx.x >> 6;
  const int lane = threadIdx.x & 63;
  const int t = blockIdx.x * 4 + wave;

  const float4* xp = (const float4*)(X + (size_t)t * DIM_D);
  float4 xv[4];
#pragma unroll
  for (int i = 0; i < 4; ++i) xv[i] = xp[lane + 64 * i];

  // fused bf16 conversion of x into the wide A buffer
#pragma unroll
  for (int i = 0; i < 4; ++i) {
    sh4 o;
    o[0] = f2bs(xv[i].x); o[1] = f2bs(xv[i].y);
    o[2] = f2bs(xv[i].z); o[3] = f2bs(xv[i].w);
    *(sh4*)&XB[(size_t)t * K1 + (lane + 64 * i) * 4] = o;
  }

  float logit[NEXP];
#pragma unroll
  for (int e = 0; e < NEXP; ++e) {
    const float4* wp = (const float4*)(RW + (size_t)e * DIM_D);
    double p = 0.0;
#pragma unroll
    for (int i = 0; i < 4; ++i) {
      float4 w = wp[lane + 64 * i];
      p += (double)xv[i].x * w.x + (double)xv[i].y * w.y +
           (double)xv[i].z * w.z + (double)xv[i].w * w.w;
    }
#pragma unroll
    for (int off = 32; off > 0; off >>= 1) p += __shfl_xor(p, off);
    logit[e] = (float)p + RB[e];
  }
  float m = logit[0];
  int am = 0;
#pragma unroll
  for (int e = 1; e < NEXP; ++e)
    if (logit[e] > m) { m = logit[e]; am = e; }
  float pr[NEXP], s = 0.f;
#pragma unroll
  for (int e = 0; e < NEXP; ++e) { pr[e] = expf(logit[e] - m); s += pr[e]; }
  const float inv = 1.f / s;
  if (lane < NEXP) {
    float r = pr[lane] * inv;
    routing_out[(size_t)t * NEXP + lane] = r;
    float y = (lane == am) ? 1.f : 0.f;
    ec_out[(size_t)t * NEXP + lane] = (y - r) + r;
  }
  if (lane == 0) idx_out[t] = am;
}

// ---------- LoRA-A GEMM (N=256), m97-style 128x128 tile ----------
// out[t*OPITCH + OOFF + gc] = bf16( gc>>5==idx[t] ? 0.5*(acc + A_b[gc]) : 0 )
template <int KM, int LDA, int OPITCH, int OOFF>
__global__ __launch_bounds__(256, 2) void lora_a_gemm(
    const short* __restrict__ A, const short* __restrict__ Bm,
    const float* __restrict__ bias, const int* __restrict__ idx,
    short* __restrict__ out)
{
  __shared__ __align__(16) short As[128 * 32];
  __shared__ __align__(16) short Bs[128 * 32];

  const int tid = threadIdx.x;
  const int m0 = blockIdx.y * 128;
  const int n0 = blockIdx.x * 128;
  const int lane = tid & 63;
  const int wv = tid >> 6;
  const int quad = lane >> 4;
  const int lrow = lane & 15;
  const int wr = wv >> 1;
  const int wc = wv & 1;
  const int r0 = tid >> 2;
  const int c4 = (tid & 3) * 8;

  f32x4 acc[4][4];
#pragma unroll
  for (int i = 0; i < 4; ++i)
#pragma unroll
    for (int j = 0; j < 4; ++j) acc[i][j] = (f32x4){0.f, 0.f, 0.f, 0.f};

  for (int it = 0; it < KM / 32; ++it) {
    const int k = it * 32;
    const short* a0 = A + (size_t)(m0 + r0) * LDA + k + c4;
    const short* b0 = Bm + (size_t)(n0 + r0) * KM + k + c4;
    async16(a0, &As[tid * 8]);
    async16(a0 + (size_t)64 * LDA, &As[2048 + tid * 8]);
    async16(b0, &Bs[tid * 8]);
    async16(b0 + (size_t)64 * KM, &Bs[2048 + tid * 8]);
    __syncthreads();

    bf16x8 af[4], bfv[4];
#pragma unroll
    for (int i = 0; i < 4; ++i)
      af[i] = *(const bf16x8*)&As[(wr * 64 + i * 16 + lrow) * 32 + quad * 8];
#pragma unroll
    for (int j = 0; j < 4; ++j)
      bfv[j] = *(const bf16x8*)&Bs[(wc * 64 + j * 16 + lrow) * 32 + quad * 8];
#pragma unroll
    for (int i = 0; i < 4; ++i)
#pragma unroll
      for (int j = 0; j < 4; ++j)
        acc[i][j] = __builtin_amdgcn_mfma_f32_16x16x32_bf16(af[i], bfv[j],
                                                            acc[i][j], 0, 0, 0);
    __syncthreads();
  }

  float cb[4];
#pragma unroll
  for (int j = 0; j < 4; ++j) cb[j] = bias[n0 + wc * 64 + j * 16 + lrow];

#pragma unroll
  for (int i = 0; i < 4; ++i) {
#pragma unroll
    for (int reg = 0; reg < 4; ++reg) {
      const int t = m0 + wr * 64 + i * 16 + quad * 4 + reg;
      const int e = idx[t];
#pragma unroll
      for (int j = 0; j < 4; ++j) {
        const int gc = n0 + wc * 64 + j * 16 + lrow;
        float v = ((gc >> 5) == e) ? 0.5f * (acc[i][j][reg] + cb[j]) : 0.f;
        out[(size_t)t * OPITCH + OOFF + gc] = f2bs(v);
      }
    }
  }
}

// ---------- 256x256 8-phase GEMM, C = A[M,K] * Bm[N,K]^T ----------
// 512 thr = 8 waves (2Mx4N); per-wave C 128x64 = acc[8][4]; BK=64 split in
// two 32-col halves (K-split) staged one half/phase via global_load_lds
// (linear LDS dest, inverse-st_16x32-swizzled global src); ds_read applies
// the same swizzle. Counted vmcnt(4) at pair boundaries, never 0 mid-loop.
// EPI: 1 = gelu(acc+bias+0.5*LB[e]) -> bf16 @ pitch POUT
//      0 = acc+bias+0.5*LB[e]       -> fp32 @ pitch POUT
template <int K, int N, int POUT, int EPI>
__global__ __launch_bounds__(512, 2) void gemm256(
    const short* __restrict__ A, const short* __restrict__ Bm,
    const float* __restrict__ LB, const float* __restrict__ bias,
    const int* __restrict__ idx, void* __restrict__ outv)
{
  static_assert(K % 128 == 0, "K must be multiple of 128");
  __shared__ __align__(16) short lds[65536];  // 128 KiB: 2 buf x (A 32K + B 32K)

  const int tid = threadIdx.x;
  const int lane = tid & 63;
  const int wv = tid >> 6;
  const int wr = wv >> 2;   // 0..1
  const int wc = wv & 3;    // 0..3
  const int quad = lane >> 4;
  const int lrow = lane & 15;

  // T1: XCD swizzle (nwg % 8 == 0 for both our grids), row-major over N
  const int gx = gridDim.x;
  int id = blockIdx.y * gx + blockIdx.x;
  const int nwg = gx * gridDim.y;
  id = (id & 7) * (nwg >> 3) + (id >> 3);
  const int m0 = (id / gx) * 256;
  const int n0 = (id % gx) * 256;

  // staging: wave wv, load jj fills subtile (wv*2+jj) of a 16KB half.
  // linear LDS byte L = subtile*1024 + lane*16; logical (row,col) of L is
  // the st_16x32-unswizzle: row = wv*32+jj*16+(lane>>2),
  // col = ((lane&3)*8) ^ (lane>=32 ? 16 : 0)   (within the 32-col half)
  const int srow = wv * 32 + (lane >> 2);
  const int scol = ((lane & 3) * 8) ^ ((lane >= 32) ? 16 : 0);
  const short* Asrc = A + (size_t)(m0 + srow) * K + scol;
  const short* Bsrc = Bm + (size_t)(n0 + srow) * K + scol;
  const int sdst = wv * 1024 + lane * 8;  // shorts; +jj*512 per load

  // ds_read swizzled inner offset (shorts): (lrow*32+quad*8) ^ (lrow&8 ? 16:0)
  const int innerA = (lrow * 32 + quad * 8) ^ ((lrow & 8) ? 16 : 0);
  const int aoff = wr * 4096 + innerA;           // + buf*32768 + ks*8192 + i*512
  const int boff = 16384 + wc * 2048 + innerA;   // + buf*32768 + ks*8192 + j*512

  f32x4 acc[8][4];
#pragma unroll
  for (int i = 0; i < 8; ++i)
#pragma unroll
    for (int j = 0; j < 4; ++j) acc[i][j] = (f32x4){0.f, 0.f, 0.f, 0.f};

  bf16x8 af[4], bfv[4];

#define STG(src, t, h, tens, buf)                                              \
  {                                                                            \
    _Pragma("unroll") for (int jj = 0; jj < 2; ++jj)                           \
        async16((src) + (size_t)(jj * 16) * K + (t) * 64 + (h) * 32,           \
                &lds[(buf) * 32768 + (tens) + (h) * 8192 + sdst + jj * 512]);  \
  }
#define RDB(ks, buf)                                                           \
  _Pragma("unroll") for (int j = 0; j < 4; ++j)                                \
      bfv[j] = *(const bf16x8*)&lds[(buf) * 32768 + (ks) * 8192 + boff + j * 512];
#define RDA(mh, ks, buf)                                                       \
  _Pragma("unroll") for (int i = 0; i < 4; ++i)                                \
      af[i] = *(const bf16x8*)&lds[(buf) * 32768 + (ks) * 8192 + aoff +        \
                                   ((mh) * 4 + i) * 512];
#define MM(mh)                                                                 \
  {                                                                            \
    __builtin_amdgcn_s_setprio(1);                                             \
    _Pragma("unroll") for (int i = 0; i < 4; ++i)                              \
    _Pragma("unroll") for (int j = 0; j < 4; ++j)                              \
        acc[(mh) * 4 + i][j] = __builtin_amdgcn_mfma_f32_16x16x32_bf16(        \
            af[i], bfv[j], acc[(mh) * 4 + i][j], 0, 0, 0);                     \
    __builtin_amdgcn_s_setprio(0);                                             \
  }
#define BARR asm volatile("s_barrier" ::: "memory")
#define WV4 asm volatile("s_waitcnt vmcnt(4)" ::: "memory")
#define WV0 asm volatile("s_waitcnt vmcnt(0)" ::: "memory")

  // prologue: tile0 -> buf0 (A_k0, B_k0, A_k1, B_k1); drain first halfpair
  STG(Asrc, 0, 0, 0, 0);
  STG(Bsrc, 0, 0, 16384, 0);
  STG(Asrc, 0, 1, 0, 0);
  STG(Bsrc, 0, 1, 16384, 0);
  WV4; BARR;

  constexpr int nIter = K / 128;
  for (int it = 0; it < nIter - 1; ++it) {
    const int t1 = 2 * it + 1, t2 = 2 * it + 2;
    // tile 2it from buf0, stage tile 2it+1 -> buf1
    RDB(0, 0); RDA(0, 0, 0); STG(Asrc, t1, 0, 0, 1);     BARR; MM(0);      BARR;
    RDA(1, 0, 0);            STG(Bsrc, t1, 0, 16384, 1); BARR; MM(1); WV4; BARR;
    RDB(1, 0); RDA(0, 1, 0); STG(Asrc, t1, 1, 0, 1);     BARR; MM(0);      BARR;
    RDA(1, 1, 0);            STG(Bsrc, t1, 1, 16384, 1); BARR; MM(1); WV4; BARR;
    // tile 2it+1 from buf1, stage tile 2it+2 -> buf0
    RDB(0, 1); RDA(0, 0, 1); STG(Asrc, t2, 0, 0, 0);     BARR; MM(0);      BARR;
    RDA(1, 0, 1);            STG(Bsrc, t2, 0, 16384, 0); BARR; MM(1); WV4; BARR;
    RDB(1, 1); RDA(0, 1, 1); STG(Asrc, t2, 1, 0, 0);     BARR; MM(0);      BARR;
    RDA(1, 1, 1);            STG(Bsrc, t2, 1, 16384, 0); BARR; MM(1); WV4; BARR;
  }
  {  // final iteration: tiles 2n-2 (buf0) and 2n-1 (buf1), no new staging
    const int t1 = 2 * nIter - 1;
    RDB(0, 0); RDA(0, 0, 0); STG(Asrc, t1, 0, 0, 1);     BARR; MM(0);      BARR;
    RDA(1, 0, 0);            STG(Bsrc, t1, 0, 16384, 1); BARR; MM(1); WV4; BARR;
    RDB(1, 0); RDA(0, 1, 0); STG(Asrc, t1, 1, 0, 1);     BARR; MM(0);      BARR;
    RDA(1, 1, 0);            STG(Bsrc, t1, 1, 16384, 1); BARR; MM(1); WV4; BARR;
    RDB(0, 1); RDA(0, 0, 1);                             BARR; MM(0);      BARR;
    RDA(1, 0, 1);                                        BARR; MM(1); WV0; BARR;
    RDB(1, 1); RDA(0, 1, 1);                             BARR; MM(0);      BARR;
    RDA(1, 1, 1);                                        BARR; MM(1);
  }
#undef STG
#undef RDB
#undef RDA
#undef MM
#undef BARR
#undef WV4
#undef WV0

  // epilogue: C row = quad*4+reg, col = lrow (dtype-independent C/D map)
  const int orow0 = m0 + wr * 128;
  const int ocol0 = n0 + wc * 64;
  float cb[4];
#pragma unroll
  for (int j = 0; j < 4; ++j) cb[j] = bias[ocol0 + j * 16 + lrow];

#pragma unroll
  for (int i = 0; i < 8; ++i) {
#pragma unroll
    for (int reg = 0; reg < 4; ++reg) {
      const int t = orow0 + i * 16 + quad * 4 + reg;
      const int e = idx[t];
      const float* lbp = LB + (size_t)e * N;
#pragma unroll
      for (int j = 0; j < 4; ++j) {
        const int gc = ocol0 + j * 16 + lrow;
        float v = acc[i][j][reg] + cb[j] + 0.5f * lbp[gc];
        if (EPI == 1) {
          v = 0.5f * v * (1.0f + erff(v * 0.70710678118654752f));
          ((short*)outv)[(size_t)t * POUT + gc] = f2bs(v);
        } else {
          ((float*)outv)[(size_t)t * POUT + gc] = v;
        }
      }
    }
  }
}

extern "C" void kernel_launch(void* const* d_in, const int* in_sizes, int n_in,
                              void* d_out, int out_size, void* d_ws, size_t ws_size,
                              hipStream_t stream) {
  (void)in_sizes; (void)n_in; (void)out_size; (void)ws_size;
  const float* x        = (const float*)d_in[0];
  const float* router_w = (const float*)d_in[1];
  const float* router_b = (const float*)d_in[2];
  const float* fc1_w    = (const float*)d_in[3];
  const float* fc1_b    = (const float*)d_in[4];
  const float* fc2_w    = (const float*)d_in[5];
  const float* fc2_b    = (const float*)d_in[6];
  const float* down_A_w = (const float*)d_in[7];   // [E,R,D]
  const float* down_A_b = (const float*)d_in[8];   // [E*R]
  const float* down_B_w = (const float*)d_in[9];   // [E,F,R]
  const float* down_B_b = (const float*)d_in[10];  // [E,F]
  const float* up_A_w   = (const float*)d_in[11];  // [E,R,F]
  const float* up_A_b   = (const float*)d_in[12];  // [E*R]
  const float* up_B_w   = (const float*)d_in[13];  // [E,D,R]
  const float* up_B_b   = (const float*)d_in[14];  // [E,D]

  // ws: idx | xbw [M,K1] | awide [M,K2] | B1w [F,K1] | B2w [D,K2] | dAb | uAb
  char* ws = (char*)d_ws;
  size_t off = 0;
  int* idxp  = (int*)ws;              off += (size_t)M_TOK * 4;
  short* xbw = (short*)(ws + off);    off += (size_t)M_TOK * K1 * 2;
  short* aw  = (short*)(ws + off);    off += (size_t)M_TOK * K2 * 2;
  short* B1w = (short*)(ws + off);    off += (size_t)DIM_F * K1 * 2;
  short* B2w = (short*)(ws + off);    off += (size_t)DIM_D * K2 * 2;
  short* dAb = (short*)(ws + off);    off += (size_t)NER * DIM_D * 2;
  short* uAb = (short*)(ws + off);    off += (size_t)NER * DIM_F * 2;

  float* out = (float*)d_out;
  float* routing = out + (size_t)M_TOK * DIM_D;
  float* ec = routing + (size_t)M_TOK * NEXP;

  // weight conversions / packing
  convert_pitched<<<2048, 256, 0, stream>>>(fc1_w, B1w, 128, K1, 524288);
  convert_pitched<<<2048, 256, 0, stream>>>(fc2_w, B2w, 512, K2, 524288);
  convert_pitched<<<128,  256, 0, stream>>>(down_A_w, dAb, 128, DIM_D, 32768);
  convert_pitched<<<512,  256, 0, stream>>>(up_A_w,   uAb, 512, DIM_F, 131072);
  pack_lorab<<<512, 256, 0, stream>>>(down_B_w, B1w, DIM_F, K1, DIM_D, 131072);
  pack_lorab<<<128, 256, 0, stream>>>(up_B_w,   B2w, DIM_D, K2, DIM_F, 32768);

  // router (+ x -> bf16 into xbw cols 0..1023)
  router_kernel<<<M_TOK / 4, 256, 0, stream>>>(x, router_w, router_b, routing,
                                               ec, idxp, xbw);
  // LoRA-A down: xbw cols 1024..1279 = mask(0.5*(x.dA^T + b))
  lora_a_gemm<DIM_D, K1, K1, DIM_D>
      <<<dim3(2, M_TOK / 128), 256, 0, stream>>>(xbw, dAb, down_A_b, idxp, xbw);
  // GEMM1: aw cols 0..4095 = gelu(xbw[.,0:1280] . B1w^T + fc1_b + 0.5*dB_b[e])
  gemm256<K1, DIM_F, K2, 1>
      <<<dim3(DIM_F / 256, M_TOK / 256), 512, 0, stream>>>(
          xbw, B1w, down_B_b, fc1_b, idxp, aw);
  // LoRA-A up: aw cols 4096..4351 = mask(0.5*(a.uA^T + b))
  lora_a_gemm<DIM_F, K2, K2, DIM_F>
      <<<dim3(2, M_TOK / 128), 256, 0, stream>>>(aw, uAb, up_A_b, idxp, aw);
  // GEMM2: out = aw[.,0:4352] . B2w^T + fc2_b + 0.5*uB_b[e]  (fp32)
  gemm256<K2, DIM_D, DIM_D, 0>
      <<<dim3(DIM_D / 256, M_TOK / 256), 512, 0, stream>>>(
          aw, B2w, up_B_b, fc2_b, idxp, out);
}